// Round 1
// baseline (4225.074 us; speedup 1.0000x reference)
//
#include <hip/hip_runtime.h>
#include <cstddef>

#define NN 50000
#define NE 400000
#define NH 4
#define ND 64
#define NC 121

// ---- float <-> order-preserving unsigned encoding (for atomicMax on floats) ----
static __device__ __forceinline__ unsigned enc_f(float f) {
    unsigned u = __float_as_uint(f);
    return (u & 0x80000000u) ? ~u : (u | 0x80000000u);
}
static __device__ __forceinline__ float dec_f(unsigned u) {
    unsigned v = (u & 0x80000000u) ? (u ^ 0x80000000u) : ~u;
    return __uint_as_float(v);
}

// ---- GEMM: C[M,Nout] = A[M,256] @ B[256,Nout], fp32, K fixed at 256 ----
// 64x64 tile, 256 threads, 4x4 per thread, BK=16 staged in LDS.
__global__ __launch_bounds__(256) void gemm_f32(const float* __restrict__ A,
                                                const float* __restrict__ B,
                                                float* __restrict__ C,
                                                int M, int Nout) {
    __shared__ __align__(16) float As[16][68];  // [k][m], +4 pad
    __shared__ __align__(16) float Bs[16][68];  // [k][n], +4 pad
    const int tid = threadIdx.x;
    const int m0 = blockIdx.x * 64;
    const int n0 = blockIdx.y * 64;
    const int tn = tid & 15;   // output col group
    const int tm = tid >> 4;   // output row group
    const int la_m = tid >> 2;        // 0..63
    const int la_k = (tid & 3) * 4;   // 0,4,8,12
    const int lb_k = tid >> 4;        // 0..15
    const int lb_n = (tid & 15) * 4;  // 0..60

    float acc[4][4] = {};

    for (int k0 = 0; k0 < 256; k0 += 16) {
        // A tile: 64 rows x 16 k, one float4 per thread along k, transposed store
        float4 av = make_float4(0.f, 0.f, 0.f, 0.f);
        if (m0 + la_m < M)
            av = *(const float4*)&A[(size_t)(m0 + la_m) * 256 + k0 + la_k];
        As[la_k + 0][la_m] = av.x;
        As[la_k + 1][la_m] = av.y;
        As[la_k + 2][la_m] = av.z;
        As[la_k + 3][la_m] = av.w;
        // B tile: 16 k x 64 n, one float4 per thread along n
        float4 bv;
        if (n0 + lb_n + 3 < Nout) {
            bv = *(const float4*)&B[(size_t)(k0 + lb_k) * Nout + n0 + lb_n];
        } else {
            float t0 = (n0 + lb_n + 0 < Nout) ? B[(size_t)(k0 + lb_k) * Nout + n0 + lb_n + 0] : 0.f;
            float t1 = (n0 + lb_n + 1 < Nout) ? B[(size_t)(k0 + lb_k) * Nout + n0 + lb_n + 1] : 0.f;
            float t2 = (n0 + lb_n + 2 < Nout) ? B[(size_t)(k0 + lb_k) * Nout + n0 + lb_n + 2] : 0.f;
            float t3 = (n0 + lb_n + 3 < Nout) ? B[(size_t)(k0 + lb_k) * Nout + n0 + lb_n + 3] : 0.f;
            bv = make_float4(t0, t1, t2, t3);
        }
        *(float4*)&Bs[lb_k][lb_n] = bv;
        __syncthreads();

        #pragma unroll
        for (int kk = 0; kk < 16; ++kk) {
            float4 a4 = *(const float4*)&As[kk][tm * 4];
            float4 b4 = *(const float4*)&Bs[kk][tn * 4];
            float av_[4] = {a4.x, a4.y, a4.z, a4.w};
            float bv_[4] = {b4.x, b4.y, b4.z, b4.w};
            #pragma unroll
            for (int i = 0; i < 4; ++i)
                #pragma unroll
                for (int j = 0; j < 4; ++j)
                    acc[i][j] += av_[i] * bv_[j];
        }
        __syncthreads();
    }

    #pragma unroll
    for (int i = 0; i < 4; ++i) {
        int m = m0 + tm * 4 + i;
        if (m >= M) continue;
        int n = n0 + tn * 4;
        if (n + 3 < Nout) {
            *(float4*)&C[(size_t)m * Nout + n] =
                make_float4(acc[i][0], acc[i][1], acc[i][2], acc[i][3]);
        } else {
            #pragma unroll
            for (int j = 0; j < 4; ++j)
                if (n + j < Nout) C[(size_t)m * Nout + n + j] = acc[i][j];
        }
    }
}

// ---- per-node attention logits: el[n,h] = sum_d feat[n,h,d]*al[h,d] (and er) ----
// one wave per (n,h)
__global__ __launch_bounds__(256) void node_attn(const float* __restrict__ feat,
                                                 const float* __restrict__ al,
                                                 const float* __restrict__ ar,
                                                 float* __restrict__ el,
                                                 float* __restrict__ er,
                                                 int D, int OUT) {
    int wid = (blockIdx.x * blockDim.x + threadIdx.x) >> 6;
    int lane = threadIdx.x & 63;
    if (wid >= NN * NH) return;
    int nidx = wid >> 2;
    int hidx = wid & 3;
    const float* frow = feat + (size_t)nidx * OUT + hidx * D;
    const float* alr = al + hidx * D;
    const float* arr = ar + hidx * D;
    float sl = 0.f, sr = 0.f;
    for (int d = lane; d < D; d += 64) {
        float f = frow[d];
        sl += f * alr[d];
        sr += f * arr[d];
    }
    #pragma unroll
    for (int off = 32; off; off >>= 1) {
        sl += __shfl_down(sl, off);
        sr += __shfl_down(sr, off);
    }
    if (lane == 0) {
        el[wid] = sl;
        er[wid] = sr;
    }
}

// ---- edge logits + segment max ----
__global__ __launch_bounds__(256) void edge_logits(const int* __restrict__ src,
                                                   const int* __restrict__ dst,
                                                   const float* __restrict__ el,
                                                   const float* __restrict__ er,
                                                   float* __restrict__ ebuf,
                                                   unsigned* __restrict__ mbuf) {
    int i = blockIdx.x * blockDim.x + threadIdx.x;
    if (i >= NE * NH) return;
    int e = i >> 2, hh = i & 3;
    int s = src[e], d = dst[e];
    float v = el[s * NH + hh] + er[d * NH + hh];
    v = v > 0.f ? v : 0.2f * v;   // leaky_relu 0.2
    ebuf[i] = v;
    atomicMax(&mbuf[d * NH + hh], enc_f(v));
}

// ---- exp(e - m[dst]) + segment sum ----
__global__ __launch_bounds__(256) void edge_exp(const int* __restrict__ dst,
                                                float* __restrict__ ebuf,
                                                const unsigned* __restrict__ mbuf,
                                                float* __restrict__ sbuf) {
    int i = blockIdx.x * blockDim.x + threadIdx.x;
    if (i >= NE * NH) return;
    int e = i >> 2, hh = i & 3;
    int d = dst[e];
    float v = expf(ebuf[i] - dec_f(mbuf[d * NH + hh]));
    ebuf[i] = v;
    atomicAdd(&sbuf[d * NH + hh], v);
}

// ---- alpha = ex / s[dst] ----
__global__ __launch_bounds__(256) void edge_alpha(const int* __restrict__ dst,
                                                  float* __restrict__ ebuf,
                                                  const float* __restrict__ sbuf) {
    int i = blockIdx.x * blockDim.x + threadIdx.x;
    if (i >= NE * NH) return;
    int e = i >> 2, hh = i & 3;
    int d = dst[e];
    ebuf[i] = ebuf[i] / sbuf[d * NH + hh];
}

// ---- message aggregation, OUT=256 (H=4, D=64): one wave per edge, float4 gather ----
__global__ __launch_bounds__(256) void msg256(const int* __restrict__ src,
                                              const int* __restrict__ dst,
                                              const float* __restrict__ ebuf,
                                              const float* __restrict__ feat,
                                              float* __restrict__ y) {
    int wid = (blockIdx.x * blockDim.x + threadIdx.x) >> 6;
    int lane = threadIdx.x & 63;
    if (wid >= NE) return;
    int s = src[wid], d = dst[wid];
    int head = lane >> 4;                 // (lane*4)/64
    float alpha = ebuf[wid * 4 + head];
    float4 f = *(const float4*)&feat[(size_t)s * 256 + lane * 4];
    float* yp = &y[(size_t)d * 256 + lane * 4];
    atomicAdd(yp + 0, alpha * f.x);
    atomicAdd(yp + 1, alpha * f.y);
    atomicAdd(yp + 2, alpha * f.z);
    atomicAdd(yp + 3, alpha * f.w);
}

// ---- message aggregation, OUT=484 (H=4, D=121): one wave per edge, scalar loop ----
__global__ __launch_bounds__(256) void msg484(const int* __restrict__ src,
                                              const int* __restrict__ dst,
                                              const float* __restrict__ ebuf,
                                              const float* __restrict__ feat,
                                              float* __restrict__ y) {
    int wid = (blockIdx.x * blockDim.x + threadIdx.x) >> 6;
    int lane = threadIdx.x & 63;
    if (wid >= NE) return;
    int s = src[wid], d = dst[wid];
    float a0 = ebuf[wid * 4 + 0];
    float a1 = ebuf[wid * 4 + 1];
    float a2 = ebuf[wid * 4 + 2];
    float a3 = ebuf[wid * 4 + 3];
    float al4[4] = {a0, a1, a2, a3};
    const float* fp = feat + (size_t)s * 484;
    float* yp = y + (size_t)d * 484;
    for (int j = lane; j < 484; j += 64) {
        int head = j / 121;
        atomicAdd(&yp[j], al4[head] * fp[j]);
    }
}

// ---- ELU in-place ----
__global__ __launch_bounds__(256) void elu_k(float* __restrict__ y, int n) {
    int i = blockIdx.x * blockDim.x + threadIdx.x;
    if (i >= n) return;
    float x = y[i];
    y[i] = x > 0.f ? x : (expf(x) - 1.f);
}

// ---- mean over heads: out[n,c] = mean_h agg3[n,h,c] ----
__global__ __launch_bounds__(256) void mean_k(const float* __restrict__ agg3,
                                              float* __restrict__ out) {
    int i = blockIdx.x * blockDim.x + threadIdx.x;
    if (i >= NN * NC) return;
    int n = i / NC;
    int c = i % NC;
    const float* p = agg3 + (size_t)n * 484 + c;
    out[i] = 0.25f * (p[0] + p[121] + p[242] + p[363]);
}

static void run_layer(const float* xin, const float* W, const float* al, const float* ar,
                      int OUT, int D, float* feat, float* y,
                      float* el, float* er, unsigned* mbuf, float* sbuf, float* ebuf,
                      const int* src, const int* dst, hipStream_t stream) {
    // GEMM first: for layer 3 the y buffer (agg3) aliases x1/x2, so feat must be
    // computed before y is zeroed.
    dim3 g((NN + 63) / 64, (OUT + 63) / 64);
    gemm_f32<<<g, 256, 0, stream>>>(xin, W, feat, NN, OUT);
    hipMemsetAsync(y, 0, (size_t)NN * OUT * sizeof(float), stream);
    hipMemsetAsync(mbuf, 0, (size_t)NN * NH * sizeof(unsigned), stream);
    hipMemsetAsync(sbuf, 0, (size_t)NN * NH * sizeof(float), stream);

    node_attn<<<NN * NH / 4, 256, 0, stream>>>(feat, al, ar, el, er, D, OUT);
    edge_logits<<<(NE * NH + 255) / 256, 256, 0, stream>>>(src, dst, el, er, ebuf, mbuf);
    edge_exp<<<(NE * NH + 255) / 256, 256, 0, stream>>>(dst, ebuf, mbuf, sbuf);
    edge_alpha<<<(NE * NH + 255) / 256, 256, 0, stream>>>(dst, ebuf, sbuf);
    if (OUT == 256)
        msg256<<<NE / 4, 256, 0, stream>>>(src, dst, ebuf, feat, y);
    else
        msg484<<<NE / 4, 256, 0, stream>>>(src, dst, ebuf, feat, y);
}

extern "C" void kernel_launch(void* const* d_in, const int* in_sizes, int n_in,
                              void* d_out, int out_size, void* d_ws, size_t ws_size,
                              hipStream_t stream) {
    const float* h   = (const float*)d_in[0];
    const int*   src = (const int*)d_in[1];
    const int*   dst = (const int*)d_in[2];
    const float* W1  = (const float*)d_in[3];
    const float* al1 = (const float*)d_in[4];
    const float* ar1 = (const float*)d_in[5];
    const float* W2  = (const float*)d_in[6];
    const float* al2 = (const float*)d_in[7];
    const float* ar2 = (const float*)d_in[8];
    const float* W3  = (const float*)d_in[9];
    const float* al3 = (const float*)d_in[10];
    const float* ar3 = (const float*)d_in[11];
    float* out = (float*)d_out;

    float* ws = (float*)d_ws;
    // workspace layout (floats)
    float*    feat = ws;                      // 24,200,000 (N*484 max)
    float*    x1   = ws + 24200000;           // 12,800,000
    float*    x2   = ws + 37000000;           // 12,800,000
    float*    el   = ws + 49800000;           // 200,000
    float*    er   = ws + 50000000;           // 200,000
    unsigned* mbuf = (unsigned*)(ws + 50200000); // 200,000
    float*    sbuf = ws + 50400000;           // 200,000
    float*    ebuf = ws + 50600000;           // 1,600,000
    float*    agg3 = x1;                      // 24,200,000 (spans x1+x2, both dead by layer 3 agg)

    // layer 1: h[N,256] -> x1[N,256]
    run_layer(h, W1, al1, ar1, 256, 64, feat, x1, el, er, mbuf, sbuf, ebuf, src, dst, stream);
    elu_k<<<NN * 256 / 256, 256, 0, stream>>>(x1, NN * 256);
    // layer 2: x1 -> x2
    run_layer(x1, W2, al2, ar2, 256, 64, feat, x2, el, er, mbuf, sbuf, ebuf, src, dst, stream);
    elu_k<<<NN * 256 / 256, 256, 0, stream>>>(x2, NN * 256);
    // layer 3: x2 -> agg3[N,4,121] (gemm reads x2 before agg3 memset overwrites it)
    run_layer(x2, W3, al3, ar3, 484, 121, feat, agg3, el, er, mbuf, sbuf, ebuf, src, dst, stream);
    mean_k<<<(NN * NC + 255) / 256, 256, 0, stream>>>(agg3, out);
}

// Round 2
// 913.264 us; speedup vs baseline: 4.6263x; 4.6263x over previous
//
#include <hip/hip_runtime.h>
#include <cstddef>

#define NN 50000
#define NE 400000
#define NH 4
#define NC 121

// ================= GEMM: C[M,Nout] = A[M,256] @ B[256,Nout], fp32 =================
// 64x64 tile, 256 threads, 4x4 per thread, BK=16 staged in LDS.
__global__ __launch_bounds__(256) void gemm_f32(const float* __restrict__ A,
                                                const float* __restrict__ B,
                                                float* __restrict__ C,
                                                int M, int Nout) {
    __shared__ __align__(16) float As[16][68];
    __shared__ __align__(16) float Bs[16][68];
    const int tid = threadIdx.x;
    const int m0 = blockIdx.x * 64;
    const int n0 = blockIdx.y * 64;
    const int tn = tid & 15;
    const int tm = tid >> 4;
    const int la_m = tid >> 2;
    const int la_k = (tid & 3) * 4;
    const int lb_k = tid >> 4;
    const int lb_n = (tid & 15) * 4;

    float acc[4][4] = {};

    for (int k0 = 0; k0 < 256; k0 += 16) {
        float4 av = make_float4(0.f, 0.f, 0.f, 0.f);
        if (m0 + la_m < M)
            av = *(const float4*)&A[(size_t)(m0 + la_m) * 256 + k0 + la_k];
        As[la_k + 0][la_m] = av.x;
        As[la_k + 1][la_m] = av.y;
        As[la_k + 2][la_m] = av.z;
        As[la_k + 3][la_m] = av.w;
        float4 bv;
        if (n0 + lb_n + 3 < Nout) {
            bv = *(const float4*)&B[(size_t)(k0 + lb_k) * Nout + n0 + lb_n];
        } else {
            float t0 = (n0 + lb_n + 0 < Nout) ? B[(size_t)(k0 + lb_k) * Nout + n0 + lb_n + 0] : 0.f;
            float t1 = (n0 + lb_n + 1 < Nout) ? B[(size_t)(k0 + lb_k) * Nout + n0 + lb_n + 1] : 0.f;
            float t2 = (n0 + lb_n + 2 < Nout) ? B[(size_t)(k0 + lb_k) * Nout + n0 + lb_n + 2] : 0.f;
            float t3 = (n0 + lb_n + 3 < Nout) ? B[(size_t)(k0 + lb_k) * Nout + n0 + lb_n + 3] : 0.f;
            bv = make_float4(t0, t1, t2, t3);
        }
        *(float4*)&Bs[lb_k][lb_n] = bv;
        __syncthreads();

        #pragma unroll
        for (int kk = 0; kk < 16; ++kk) {
            float4 a4 = *(const float4*)&As[kk][tm * 4];
            float4 b4 = *(const float4*)&Bs[kk][tn * 4];
            float av_[4] = {a4.x, a4.y, a4.z, a4.w};
            float bv_[4] = {b4.x, b4.y, b4.z, b4.w};
            #pragma unroll
            for (int i = 0; i < 4; ++i)
                #pragma unroll
                for (int j = 0; j < 4; ++j)
                    acc[i][j] += av_[i] * bv_[j];
        }
        __syncthreads();
    }

    #pragma unroll
    for (int i = 0; i < 4; ++i) {
        int m = m0 + tm * 4 + i;
        if (m >= M) continue;
        int n = n0 + tn * 4;
        if (n + 3 < Nout) {
            *(float4*)&C[(size_t)m * Nout + n] =
                make_float4(acc[i][0], acc[i][1], acc[i][2], acc[i][3]);
        } else {
            #pragma unroll
            for (int j = 0; j < 4; ++j)
                if (n + j < Nout) C[(size_t)m * Nout + n + j] = acc[i][j];
        }
    }
}

// ================= per-node attention logits =================
// one wave per (n,h): el[n,h] = sum_d feat[n,h,d]*al[h,d]; er likewise
__global__ __launch_bounds__(256) void node_attn(const float* __restrict__ feat,
                                                 const float* __restrict__ al,
                                                 const float* __restrict__ ar,
                                                 float* __restrict__ el,
                                                 float* __restrict__ er,
                                                 int D, int OUT) {
    int wid = (blockIdx.x * blockDim.x + threadIdx.x) >> 6;
    int lane = threadIdx.x & 63;
    if (wid >= NN * NH) return;
    int nidx = wid >> 2;
    int hidx = wid & 3;
    const float* frow = feat + (size_t)nidx * OUT + hidx * D;
    const float* alr = al + hidx * D;
    const float* arr = ar + hidx * D;
    float sl = 0.f, sr = 0.f;
    for (int d = lane; d < D; d += 64) {
        float f = frow[d];
        sl += f * alr[d];
        sr += f * arr[d];
    }
    #pragma unroll
    for (int off = 32; off; off >>= 1) {
        sl += __shfl_down(sl, off);
        sr += __shfl_down(sr, off);
    }
    if (lane == 0) {
        el[wid] = sl;
        er[wid] = sr;
    }
}

// ================= CSR build =================
__global__ __launch_bounds__(256) void hist_k(const int* __restrict__ dst, int* __restrict__ deg) {
    int e = blockIdx.x * blockDim.x + threadIdx.x;
    if (e < NE) atomicAdd(&deg[dst[e]], 1);
}

// per-block inclusive scan -> exclusive-within-block + block partial sums
__global__ __launch_bounds__(256) void scan1(const int* __restrict__ deg,
                                             int* __restrict__ excl,
                                             int* __restrict__ partials) {
    __shared__ int sh[256];
    int i = blockIdx.x * 256 + threadIdx.x;
    int v = (i < NN) ? deg[i] : 0;
    sh[threadIdx.x] = v;
    __syncthreads();
    for (int off = 1; off < 256; off <<= 1) {
        int t = (threadIdx.x >= off) ? sh[threadIdx.x - off] : 0;
        __syncthreads();
        sh[threadIdx.x] += t;
        __syncthreads();
    }
    if (i < NN) excl[i] = sh[threadIdx.x] - v;
    if (threadIdx.x == 255) partials[blockIdx.x] = sh[255];
}

// single-block exclusive scan of block partials (nb <= 256)
__global__ __launch_bounds__(256) void scan2(int* __restrict__ partials, int nb) {
    __shared__ int sh[256];
    int t = threadIdx.x;
    int v = (t < nb) ? partials[t] : 0;
    sh[t] = v;
    __syncthreads();
    for (int off = 1; off < 256; off <<= 1) {
        int x = (t >= off) ? sh[t - off] : 0;
        __syncthreads();
        sh[t] += x;
        __syncthreads();
    }
    if (t < nb) partials[t] = sh[t] - v;
}

__global__ __launch_bounds__(256) void scan3(const int* __restrict__ excl,
                                             const int* __restrict__ partials,
                                             int* __restrict__ rowptr) {
    int i = blockIdx.x * 256 + threadIdx.x;
    if (i < NN) rowptr[i] = excl[i] + partials[blockIdx.x];
}

__global__ __launch_bounds__(256) void scatter_k(const int* __restrict__ src,
                                                 const int* __restrict__ dst,
                                                 const int* __restrict__ rowptr,
                                                 int* __restrict__ cursor,
                                                 int* __restrict__ ssrc) {
    int e = blockIdx.x * blockDim.x + threadIdx.x;
    if (e >= NE) return;
    int d = dst[e];
    int p = atomicAdd(&cursor[d], 1);
    ssrc[rowptr[d] + p] = src[e];
}

// ================= fused softmax + aggregation, OUT=256 (H=4, D=64) =================
// one wave per dst node; lane owns 4 contiguous output floats; optional fused ELU.
__global__ __launch_bounds__(256) void agg256(const int* __restrict__ rowptr,
                                              const int* __restrict__ deg,
                                              const int* __restrict__ ssrc,
                                              const float* __restrict__ el,
                                              const float* __restrict__ er,
                                              const float* __restrict__ feat,
                                              float* __restrict__ y,
                                              int do_elu) {
    int wid = (blockIdx.x * blockDim.x + threadIdx.x) >> 6;
    int lane = threadIdx.x & 63;
    if (wid >= NN) return;
    int n = wid;
    int start = rowptr[n], cnt = deg[n];
    int head = lane >> 4;
    float ern = er[n * 4 + head];
    // pass 1: per-head max logit over incoming edges
    float m = -1e30f;
    for (int k = 0; k < cnt; ++k) {
        int s = ssrc[start + k];
        float v = el[s * 4 + head] + ern;
        v = v > 0.f ? v : 0.2f * v;
        m = fmaxf(m, v);
    }
    // pass 2: exp + weighted accumulate
    float ax = 0.f, ay = 0.f, az = 0.f, aw = 0.f, ssum = 0.f;
    for (int k = 0; k < cnt; ++k) {
        int s = ssrc[start + k];
        float v = el[s * 4 + head] + ern;
        v = v > 0.f ? v : 0.2f * v;
        float ex = __expf(v - m);
        ssum += ex;
        float4 f = *(const float4*)&feat[(size_t)s * 256 + lane * 4];
        ax += ex * f.x; ay += ex * f.y; az += ex * f.z; aw += ex * f.w;
    }
    float inv = cnt ? 1.0f / ssum : 0.f;
    ax *= inv; ay *= inv; az *= inv; aw *= inv;
    if (do_elu) {
        ax = ax > 0.f ? ax : (__expf(ax) - 1.f);
        ay = ay > 0.f ? ay : (__expf(ay) - 1.f);
        az = az > 0.f ? az : (__expf(az) - 1.f);
        aw = aw > 0.f ? aw : (__expf(aw) - 1.f);
    }
    *(float4*)&y[(size_t)n * 256 + lane * 4] = make_float4(ax, ay, az, aw);
}

// ================= fused softmax + aggregation + head-mean, OUT=484 (H=4, D=121) ====
// one wave per dst node; lane owns classes c=lane and c=lane+64; writes d_out.
__global__ __launch_bounds__(256) void agg484(const int* __restrict__ rowptr,
                                              const int* __restrict__ deg,
                                              const int* __restrict__ ssrc,
                                              const float* __restrict__ el,
                                              const float* __restrict__ er,
                                              const float* __restrict__ feat,
                                              float* __restrict__ out) {
    int wid = (blockIdx.x * blockDim.x + threadIdx.x) >> 6;
    int lane = threadIdx.x & 63;
    if (wid >= NN) return;
    int n = wid;
    int start = rowptr[n], cnt = deg[n];
    float er0 = er[n * 4 + 0], er1 = er[n * 4 + 1], er2 = er[n * 4 + 2], er3 = er[n * 4 + 3];
    // pass 1: per-head max (all lanes redundantly)
    float m0 = -1e30f, m1 = -1e30f, m2 = -1e30f, m3 = -1e30f;
    for (int k = 0; k < cnt; ++k) {
        int s = ssrc[start + k];
        float v0 = el[s * 4 + 0] + er0; v0 = v0 > 0.f ? v0 : 0.2f * v0; m0 = fmaxf(m0, v0);
        float v1 = el[s * 4 + 1] + er1; v1 = v1 > 0.f ? v1 : 0.2f * v1; m1 = fmaxf(m1, v1);
        float v2 = el[s * 4 + 2] + er2; v2 = v2 > 0.f ? v2 : 0.2f * v2; m2 = fmaxf(m2, v2);
        float v3 = el[s * 4 + 3] + er3; v3 = v3 > 0.f ? v3 : 0.2f * v3; m3 = fmaxf(m3, v3);
    }
    const int c1 = lane;                       // < 121 always
    const int c2v = (lane + 64 < NC) ? lane + 64 : NC - 1;  // clamped (discard at write)
    float a0x = 0.f, a0y = 0.f, a1x = 0.f, a1y = 0.f;
    float a2x = 0.f, a2y = 0.f, a3x = 0.f, a3y = 0.f;
    float s0 = 0.f, s1 = 0.f, s2 = 0.f, s3 = 0.f;
    for (int k = 0; k < cnt; ++k) {
        int s = ssrc[start + k];
        const float* fr = feat + (size_t)s * 484;
        float v0 = el[s * 4 + 0] + er0; v0 = v0 > 0.f ? v0 : 0.2f * v0;
        float v1 = el[s * 4 + 1] + er1; v1 = v1 > 0.f ? v1 : 0.2f * v1;
        float v2 = el[s * 4 + 2] + er2; v2 = v2 > 0.f ? v2 : 0.2f * v2;
        float v3 = el[s * 4 + 3] + er3; v3 = v3 > 0.f ? v3 : 0.2f * v3;
        float e0 = __expf(v0 - m0), e1 = __expf(v1 - m1);
        float e2 = __expf(v2 - m2), e3 = __expf(v3 - m3);
        s0 += e0; s1 += e1; s2 += e2; s3 += e3;
        a0x += e0 * fr[0 * NC + c1]; a0y += e0 * fr[0 * NC + c2v];
        a1x += e1 * fr[1 * NC + c1]; a1y += e1 * fr[1 * NC + c2v];
        a2x += e2 * fr[2 * NC + c1]; a2y += e2 * fr[2 * NC + c2v];
        a3x += e3 * fr[3 * NC + c1]; a3y += e3 * fr[3 * NC + c2v];
    }
    float o1 = 0.f, o2 = 0.f;
    if (cnt) {
        float i0 = 1.f / s0, i1 = 1.f / s1, i2 = 1.f / s2, i3 = 1.f / s3;
        o1 = 0.25f * (a0x * i0 + a1x * i1 + a2x * i2 + a3x * i3);
        o2 = 0.25f * (a0y * i0 + a1y * i1 + a2y * i2 + a3y * i3);
    }
    out[(size_t)n * NC + c1] = o1;
    if (lane + 64 < NC) out[(size_t)n * NC + lane + 64] = o2;
}

extern "C" void kernel_launch(void* const* d_in, const int* in_sizes, int n_in,
                              void* d_out, int out_size, void* d_ws, size_t ws_size,
                              hipStream_t stream) {
    const float* h   = (const float*)d_in[0];
    const int*   src = (const int*)d_in[1];
    const int*   dst = (const int*)d_in[2];
    const float* W1  = (const float*)d_in[3];
    const float* al1 = (const float*)d_in[4];
    const float* ar1 = (const float*)d_in[5];
    const float* W2  = (const float*)d_in[6];
    const float* al2 = (const float*)d_in[7];
    const float* ar2 = (const float*)d_in[8];
    const float* W3  = (const float*)d_in[9];
    const float* al3 = (const float*)d_in[10];
    const float* ar3 = (const float*)d_in[11];
    float* out = (float*)d_out;

    float* ws = (float*)d_ws;
    // workspace layout (float units)
    float* feat = ws;                    // 24,200,000 (N*484 max)
    float* x1   = ws + 24200000;         // 12,800,000
    float* x2   = ws + 37000000;         // 12,800,000
    float* el   = ws + 49800000;         // 200,000
    float* er   = ws + 50000000;         // 200,000
    int* ibase  = (int*)(ws + 50200000);
    int* deg      = ibase;               // 50,000
    int* excl     = ibase + 50000;       // 50,000
    int* partials = ibase + 100000;      // 256
    int* rowptr   = ibase + 100256;      // 50,000
    int* cursor   = ibase + 150256;      // 50,000
    int* ssrc     = ibase + 200256;      // 400,000

    const int NB = (NN + 255) / 256;     // 196 blocks for node-sized scans

    // ---- CSR build (once; shared by all 3 layers) ----
    hipMemsetAsync(deg, 0, NN * sizeof(int), stream);
    hipMemsetAsync(cursor, 0, NN * sizeof(int), stream);
    hist_k<<<(NE + 255) / 256, 256, 0, stream>>>(dst, deg);
    scan1<<<NB, 256, 0, stream>>>(deg, excl, partials);
    scan2<<<1, 256, 0, stream>>>(partials, NB);
    scan3<<<NB, 256, 0, stream>>>(excl, partials, rowptr);
    scatter_k<<<(NE + 255) / 256, 256, 0, stream>>>(src, dst, rowptr, cursor, ssrc);

    dim3 g256((NN + 63) / 64, 4);   // 64x64 tiles over [N,256]
    dim3 g484((NN + 63) / 64, 8);   // 64x64 tiles over [N,484]
    const int AGG_BLOCKS = (NN * 64 + 255) / 256;  // one wave per node
    const int ATTN_BLOCKS = NN * NH / 4;           // one wave per (n,h)

    // ---- layer 1: h -> feat -> x1 (with fused ELU) ----
    gemm_f32<<<g256, 256, 0, stream>>>(h, W1, feat, NN, 256);
    node_attn<<<ATTN_BLOCKS, 256, 0, stream>>>(feat, al1, ar1, el, er, 64, 256);
    agg256<<<AGG_BLOCKS, 256, 0, stream>>>(rowptr, deg, ssrc, el, er, feat, x1, 1);

    // ---- layer 2: x1 -> feat -> x2 (with fused ELU) ----
    gemm_f32<<<g256, 256, 0, stream>>>(x1, W2, feat, NN, 256);
    node_attn<<<ATTN_BLOCKS, 256, 0, stream>>>(feat, al2, ar2, el, er, 64, 256);
    agg256<<<AGG_BLOCKS, 256, 0, stream>>>(rowptr, deg, ssrc, el, er, feat, x2, 1);

    // ---- layer 3: x2 -> feat -> out (fused softmax+agg+head-mean) ----
    gemm_f32<<<g484, 256, 0, stream>>>(x2, W3, feat, NN, 484);
    node_attn<<<ATTN_BLOCKS, 256, 0, stream>>>(feat, al3, ar3, el, er, 121, 484);
    agg484<<<AGG_BLOCKS, 256, 0, stream>>>(rowptr, deg, ssrc, el, er, feat, out);
}

// Round 3
// 649.790 us; speedup vs baseline: 6.5022x; 1.4055x over previous
//
#include <hip/hip_runtime.h>
#include <cstddef>

#define NN 50000
#define NE 400000
#define NH 4
#define NC 121

typedef __attribute__((ext_vector_type(8))) short short8;
typedef __attribute__((ext_vector_type(4))) float f32x4;

// fp32 -> bf16 round-to-nearest-even
static __device__ __forceinline__ unsigned short f2bf(float f) {
    unsigned u = __float_as_uint(f);
    u += 0x7fffu + ((u >> 16) & 1u);
    return (unsigned short)(u >> 16);
}

// ================= cast kernels =================
__global__ __launch_bounds__(256) void cast_x(const float* __restrict__ in,
                                              unsigned short* __restrict__ out, int n4) {
    int i = blockIdx.x * blockDim.x + threadIdx.x;
    if (i >= n4) return;
    float4 v = *(const float4*)&in[i * 4];
    ushort4 o;
    o.x = f2bf(v.x); o.y = f2bf(v.y); o.z = f2bf(v.z); o.w = f2bf(v.w);
    *(ushort4*)&out[i * 4] = o;
}

// B[K=256][N] fp32 -> BT[Npad][256] bf16 (transposed, zero-padded rows)
__global__ __launch_bounds__(256) void cast_BT(const float* __restrict__ B,
                                               unsigned short* __restrict__ BT,
                                               int N, int Npad) {
    int i = blockIdx.x * blockDim.x + threadIdx.x;
    if (i >= Npad * 256) return;
    int n = i >> 8, k = i & 255;
    float v = (n < N) ? B[(size_t)k * N + n] : 0.f;
    BT[i] = f2bf(v);
}

// ================= MFMA GEMM: C[M,Nout] = A[M,256] @ B[256,Nout] =================
// A bf16 [M][256] row-major; BT bf16 [Npad][256] (B transposed); C fp32 [M][Nout].
// 128x128 tile, 256 threads (4 waves in 2x2), BK=32, 16x16x32 bf16 MFMA, 4x4 frags/wave.
__global__ __launch_bounds__(256) void gemm_bf16(const unsigned short* __restrict__ A,
                                                 const unsigned short* __restrict__ BT,
                                                 float* __restrict__ C,
                                                 int M, int Nout) {
    __shared__ __align__(16) unsigned short Alds[128 * 32];
    __shared__ __align__(16) unsigned short Blds[128 * 32];
    const int tid = threadIdx.x;
    const int wave = tid >> 6;
    const int lane = tid & 63;
    const int quad = lane >> 4;
    const int ml = lane & 15;
    const int m0 = blockIdx.x * 128;
    const int n0 = blockIdx.y * 128;
    const int wm0 = (wave >> 1) * 64;
    const int wn0 = (wave & 1) * 64;
    const int r = tid >> 2;          // 0..63 staging row
    const int c8 = (tid & 3) * 8;    // 0,8,16,24 staging k-offset

    f32x4 acc[4][4] = {};

    for (int k0 = 0; k0 < 256; k0 += 32) {
        #pragma unroll
        for (int p = 0; p < 2; ++p) {
            int rr = r + p * 64;
            int m = m0 + rr;
            uint4 va = make_uint4(0u, 0u, 0u, 0u);
            if (m < M) va = *(const uint4*)&A[(size_t)m * 256 + k0 + c8];
            *(uint4*)&Alds[rr * 32 + c8] = va;
            int n = n0 + rr;  // BT padded to grid => always in bounds
            uint4 vb = *(const uint4*)&BT[(size_t)n * 256 + k0 + c8];
            *(uint4*)&Blds[rr * 32 + c8] = vb;
        }
        __syncthreads();

        short8 af[4], bf[4];
        #pragma unroll
        for (int i = 0; i < 4; ++i)
            af[i] = *(const short8*)&Alds[(wm0 + i * 16 + ml) * 32 + quad * 8];
        #pragma unroll
        for (int j = 0; j < 4; ++j)
            bf[j] = *(const short8*)&Blds[(wn0 + j * 16 + ml) * 32 + quad * 8];
        #pragma unroll
        for (int i = 0; i < 4; ++i)
            #pragma unroll
            for (int j = 0; j < 4; ++j)
                acc[i][j] = __builtin_amdgcn_mfma_f32_16x16x32_bf16(af[i], bf[j], acc[i][j], 0, 0, 0);
        __syncthreads();
    }

    // C/D layout: col = lane&15, row = quad*4 + reg  [verified m89/m91]
    #pragma unroll
    for (int i = 0; i < 4; ++i) {
        #pragma unroll
        for (int reg = 0; reg < 4; ++reg) {
            int m = m0 + wm0 + i * 16 + quad * 4 + reg;
            if (m >= M) continue;
            #pragma unroll
            for (int j = 0; j < 4; ++j) {
                int n = n0 + wn0 + j * 16 + ml;
                if (n < Nout) C[(size_t)m * Nout + n] = acc[i][j][reg];
            }
        }
    }
}

// ================= per-node attention logits =================
__global__ __launch_bounds__(256) void node_attn(const float* __restrict__ feat,
                                                 const float* __restrict__ al,
                                                 const float* __restrict__ ar,
                                                 float* __restrict__ el,
                                                 float* __restrict__ er,
                                                 int D, int OUT) {
    int wid = (blockIdx.x * blockDim.x + threadIdx.x) >> 6;
    int lane = threadIdx.x & 63;
    if (wid >= NN * NH) return;
    int nidx = wid >> 2;
    int hidx = wid & 3;
    const float* frow = feat + (size_t)nidx * OUT + hidx * D;
    const float* alr = al + hidx * D;
    const float* arr = ar + hidx * D;
    float sl = 0.f, sr = 0.f;
    for (int d = lane; d < D; d += 64) {
        float f = frow[d];
        sl += f * alr[d];
        sr += f * arr[d];
    }
    #pragma unroll
    for (int off = 32; off; off >>= 1) {
        sl += __shfl_down(sl, off);
        sr += __shfl_down(sr, off);
    }
    if (lane == 0) {
        el[wid] = sl;
        er[wid] = sr;
    }
}

// ================= CSR build =================
__global__ __launch_bounds__(256) void hist_k(const int* __restrict__ dst, int* __restrict__ deg) {
    int e = blockIdx.x * blockDim.x + threadIdx.x;
    if (e < NE) atomicAdd(&deg[dst[e]], 1);
}

__global__ __launch_bounds__(256) void scan1(const int* __restrict__ deg,
                                             int* __restrict__ excl,
                                             int* __restrict__ partials) {
    __shared__ int sh[256];
    int i = blockIdx.x * 256 + threadIdx.x;
    int v = (i < NN) ? deg[i] : 0;
    sh[threadIdx.x] = v;
    __syncthreads();
    for (int off = 1; off < 256; off <<= 1) {
        int t = (threadIdx.x >= off) ? sh[threadIdx.x - off] : 0;
        __syncthreads();
        sh[threadIdx.x] += t;
        __syncthreads();
    }
    if (i < NN) excl[i] = sh[threadIdx.x] - v;
    if (threadIdx.x == 255) partials[blockIdx.x] = sh[255];
}

__global__ __launch_bounds__(256) void scan2(int* __restrict__ partials, int nb) {
    __shared__ int sh[256];
    int t = threadIdx.x;
    int v = (t < nb) ? partials[t] : 0;
    sh[t] = v;
    __syncthreads();
    for (int off = 1; off < 256; off <<= 1) {
        int x = (t >= off) ? sh[t - off] : 0;
        __syncthreads();
        sh[t] += x;
        __syncthreads();
    }
    if (t < nb) partials[t] = sh[t] - v;
}

__global__ __launch_bounds__(256) void scan3(const int* __restrict__ excl,
                                             const int* __restrict__ partials,
                                             int* __restrict__ rowptr) {
    int i = blockIdx.x * 256 + threadIdx.x;
    if (i < NN) rowptr[i] = excl[i] + partials[blockIdx.x];
}

__global__ __launch_bounds__(256) void scatter_k(const int* __restrict__ src,
                                                 const int* __restrict__ dst,
                                                 const int* __restrict__ rowptr,
                                                 int* __restrict__ cursor,
                                                 int* __restrict__ ssrc) {
    int e = blockIdx.x * blockDim.x + threadIdx.x;
    if (e >= NE) return;
    int d = dst[e];
    int p = atomicAdd(&cursor[d], 1);
    ssrc[rowptr[d] + p] = src[e];
}

// ================= fused softmax + aggregation + ELU, OUT=256, bf16 output ==========
__global__ __launch_bounds__(256) void agg256(const int* __restrict__ rowptr,
                                              const int* __restrict__ deg,
                                              const int* __restrict__ ssrc,
                                              const float* __restrict__ el,
                                              const float* __restrict__ er,
                                              const float* __restrict__ feat,
                                              unsigned short* __restrict__ ybf) {
    int wid = (blockIdx.x * blockDim.x + threadIdx.x) >> 6;
    int lane = threadIdx.x & 63;
    if (wid >= NN) return;
    int n = wid;
    int start = rowptr[n], cnt = deg[n];
    int head = lane >> 4;
    float ern = er[n * 4 + head];
    float m = -1e30f;
    for (int k = 0; k < cnt; ++k) {
        int s = ssrc[start + k];
        float v = el[s * 4 + head] + ern;
        v = v > 0.f ? v : 0.2f * v;
        m = fmaxf(m, v);
    }
    float ax = 0.f, ay = 0.f, az = 0.f, aw = 0.f, ssum = 0.f;
    for (int k = 0; k < cnt; ++k) {
        int s = ssrc[start + k];
        float v = el[s * 4 + head] + ern;
        v = v > 0.f ? v : 0.2f * v;
        float ex = __expf(v - m);
        ssum += ex;
        float4 f = *(const float4*)&feat[(size_t)s * 256 + lane * 4];
        ax += ex * f.x; ay += ex * f.y; az += ex * f.z; aw += ex * f.w;
    }
    float inv = cnt ? 1.0f / ssum : 0.f;
    ax *= inv; ay *= inv; az *= inv; aw *= inv;
    ax = ax > 0.f ? ax : (__expf(ax) - 1.f);
    ay = ay > 0.f ? ay : (__expf(ay) - 1.f);
    az = az > 0.f ? az : (__expf(az) - 1.f);
    aw = aw > 0.f ? aw : (__expf(aw) - 1.f);
    ushort4 o;
    o.x = f2bf(ax); o.y = f2bf(ay); o.z = f2bf(az); o.w = f2bf(aw);
    *(ushort4*)&ybf[(size_t)n * 256 + lane * 4] = o;
}

// ================= fused softmax + aggregation + head-mean, OUT=484 -> d_out ========
__global__ __launch_bounds__(256) void agg484(const int* __restrict__ rowptr,
                                              const int* __restrict__ deg,
                                              const int* __restrict__ ssrc,
                                              const float* __restrict__ el,
                                              const float* __restrict__ er,
                                              const float* __restrict__ feat,
                                              float* __restrict__ out) {
    int wid = (blockIdx.x * blockDim.x + threadIdx.x) >> 6;
    int lane = threadIdx.x & 63;
    if (wid >= NN) return;
    int n = wid;
    int start = rowptr[n], cnt = deg[n];
    float er0 = er[n * 4 + 0], er1 = er[n * 4 + 1], er2 = er[n * 4 + 2], er3 = er[n * 4 + 3];
    float m0 = -1e30f, m1 = -1e30f, m2 = -1e30f, m3 = -1e30f;
    for (int k = 0; k < cnt; ++k) {
        int s = ssrc[start + k];
        float v0 = el[s * 4 + 0] + er0; v0 = v0 > 0.f ? v0 : 0.2f * v0; m0 = fmaxf(m0, v0);
        float v1 = el[s * 4 + 1] + er1; v1 = v1 > 0.f ? v1 : 0.2f * v1; m1 = fmaxf(m1, v1);
        float v2 = el[s * 4 + 2] + er2; v2 = v2 > 0.f ? v2 : 0.2f * v2; m2 = fmaxf(m2, v2);
        float v3 = el[s * 4 + 3] + er3; v3 = v3 > 0.f ? v3 : 0.2f * v3; m3 = fmaxf(m3, v3);
    }
    const int c1 = lane;
    const int c2v = (lane + 64 < NC) ? lane + 64 : NC - 1;
    float a0x = 0.f, a0y = 0.f, a1x = 0.f, a1y = 0.f;
    float a2x = 0.f, a2y = 0.f, a3x = 0.f, a3y = 0.f;
    float s0 = 0.f, s1 = 0.f, s2 = 0.f, s3 = 0.f;
    for (int k = 0; k < cnt; ++k) {
        int s = ssrc[start + k];
        const float* fr = feat + (size_t)s * 484;
        float v0 = el[s * 4 + 0] + er0; v0 = v0 > 0.f ? v0 : 0.2f * v0;
        float v1 = el[s * 4 + 1] + er1; v1 = v1 > 0.f ? v1 : 0.2f * v1;
        float v2 = el[s * 4 + 2] + er2; v2 = v2 > 0.f ? v2 : 0.2f * v2;
        float v3 = el[s * 4 + 3] + er3; v3 = v3 > 0.f ? v3 : 0.2f * v3;
        float e0 = __expf(v0 - m0), e1 = __expf(v1 - m1);
        float e2 = __expf(v2 - m2), e3 = __expf(v3 - m3);
        s0 += e0; s1 += e1; s2 += e2; s3 += e3;
        a0x += e0 * fr[0 * NC + c1]; a0y += e0 * fr[0 * NC + c2v];
        a1x += e1 * fr[1 * NC + c1]; a1y += e1 * fr[1 * NC + c2v];
        a2x += e2 * fr[2 * NC + c1]; a2y += e2 * fr[2 * NC + c2v];
        a3x += e3 * fr[3 * NC + c1]; a3y += e3 * fr[3 * NC + c2v];
    }
    float o1 = 0.f, o2 = 0.f;
    if (cnt) {
        float i0 = 1.f / s0, i1 = 1.f / s1, i2 = 1.f / s2, i3 = 1.f / s3;
        o1 = 0.25f * (a0x * i0 + a1x * i1 + a2x * i2 + a3x * i3);
        o2 = 0.25f * (a0y * i0 + a1y * i1 + a2y * i2 + a3y * i3);
    }
    out[(size_t)n * NC + c1] = o1;
    if (lane + 64 < NC) out[(size_t)n * NC + lane + 64] = o2;
}

extern "C" void kernel_launch(void* const* d_in, const int* in_sizes, int n_in,
                              void* d_out, int out_size, void* d_ws, size_t ws_size,
                              hipStream_t stream) {
    const float* h   = (const float*)d_in[0];
    const int*   src = (const int*)d_in[1];
    const int*   dst = (const int*)d_in[2];
    const float* W1  = (const float*)d_in[3];
    const float* al1 = (const float*)d_in[4];
    const float* ar1 = (const float*)d_in[5];
    const float* W2  = (const float*)d_in[6];
    const float* al2 = (const float*)d_in[7];
    const float* ar2 = (const float*)d_in[8];
    const float* W3  = (const float*)d_in[9];
    const float* al3 = (const float*)d_in[10];
    const float* ar3 = (const float*)d_in[11];
    float* out = (float*)d_out;

    float* ws = (float*)d_ws;
    // workspace layout (float units)
    float* feat = ws;                            // 24,200,000 (N*484 max)
    float* el   = ws + 24200000;                 // 200,000
    float* er   = ws + 24400000;                 // 200,000
    unsigned short* h_bf = (unsigned short*)(ws + 24600000);  // 12.8M bf16 = 6.4M f
    unsigned short* x_bf = (unsigned short*)(ws + 31000000);  // 12.8M bf16 = 6.4M f
    unsigned short* BT1  = (unsigned short*)(ws + 37400000);  // 65,536 bf16
    unsigned short* BT2  = (unsigned short*)(ws + 37432768);  // 65,536 bf16
    unsigned short* BT3  = (unsigned short*)(ws + 37465536);  // 131,072 bf16
    int* ibase  = (int*)(ws + 37531072);
    int* deg      = ibase;                       // 50,000
    int* excl     = ibase + 50000;               // 50,000
    int* partials = ibase + 100000;              // 256
    int* rowptr   = ibase + 100256;              // 50,000
    int* cursor   = ibase + 150256;              // 50,000
    int* ssrc     = ibase + 200256;              // 400,000

    const int NB = (NN + 255) / 256;

    // ---- CSR build (shared by all 3 layers) ----
    hipMemsetAsync(deg, 0, NN * sizeof(int), stream);
    hipMemsetAsync(cursor, 0, NN * sizeof(int), stream);
    hist_k<<<(NE + 255) / 256, 256, 0, stream>>>(dst, deg);
    scan1<<<NB, 256, 0, stream>>>(deg, excl, partials);
    scan2<<<1, 256, 0, stream>>>(partials, NB);
    scan3<<<NB, 256, 0, stream>>>(excl, partials, rowptr);
    scatter_k<<<(NE + 255) / 256, 256, 0, stream>>>(src, dst, rowptr, cursor, ssrc);

    // ---- weight/input casts ----
    cast_x<<<(NN * 256 / 4 + 255) / 256, 256, 0, stream>>>(h, h_bf, NN * 256 / 4);
    cast_BT<<<(256 * 256 + 255) / 256, 256, 0, stream>>>(W1, BT1, 256, 256);
    cast_BT<<<(256 * 256 + 255) / 256, 256, 0, stream>>>(W2, BT2, 256, 256);
    cast_BT<<<(512 * 256 + 255) / 256, 256, 0, stream>>>(W3, BT3, 484, 512);

    dim3 g256((NN + 127) / 128, 2);
    dim3 g484((NN + 127) / 128, 4);
    const int AGG_BLOCKS = (NN * 64 + 255) / 256;
    const int ATTN_BLOCKS = NN * NH / 4;

    // ---- layer 1 ----
    gemm_bf16<<<g256, 256, 0, stream>>>(h_bf, BT1, feat, NN, 256);
    node_attn<<<ATTN_BLOCKS, 256, 0, stream>>>(feat, al1, ar1, el, er, 64, 256);
    agg256<<<AGG_BLOCKS, 256, 0, stream>>>(rowptr, deg, ssrc, el, er, feat, x_bf);

    // ---- layer 2 ----
    gemm_bf16<<<g256, 256, 0, stream>>>(x_bf, BT2, feat, NN, 256);
    node_attn<<<ATTN_BLOCKS, 256, 0, stream>>>(feat, al2, ar2, el, er, 64, 256);
    agg256<<<AGG_BLOCKS, 256, 0, stream>>>(rowptr, deg, ssrc, el, er, feat, x_bf);

    // ---- layer 3 ----
    gemm_bf16<<<g484, 256, 0, stream>>>(x_bf, BT3, feat, NN, 484);
    node_attn<<<ATTN_BLOCKS, 256, 0, stream>>>(feat, al3, ar3, el, er, 121, 484);
    agg484<<<AGG_BLOCKS, 256, 0, stream>>>(rowptr, deg, ssrc, el, er, feat, out);
}

// Round 4
// 558.489 us; speedup vs baseline: 7.5652x; 1.1635x over previous
//
#include <hip/hip_runtime.h>
#include <cstddef>

#define NN 50000
#define NE 400000
#define NH 4
#define NC 121

typedef __attribute__((ext_vector_type(8))) short short8;
typedef __attribute__((ext_vector_type(4))) float f32x4;

// fp32 -> bf16 round-to-nearest-even
static __device__ __forceinline__ unsigned short f2bf(float f) {
    unsigned u = __float_as_uint(f);
    u += 0x7fffu + ((u >> 16) & 1u);
    return (unsigned short)(u >> 16);
}
static __device__ __forceinline__ float bf2f(unsigned short u) {
    return __uint_as_float(((unsigned)u) << 16);
}

// ================= cast kernels =================
__global__ __launch_bounds__(256) void cast_x(const float* __restrict__ in,
                                              unsigned short* __restrict__ out, int n4) {
    int i = blockIdx.x * blockDim.x + threadIdx.x;
    if (i >= n4) return;
    float4 v = *(const float4*)&in[i * 4];
    ushort4 o;
    o.x = f2bf(v.x); o.y = f2bf(v.y); o.z = f2bf(v.z); o.w = f2bf(v.w);
    *(ushort4*)&out[i * 4] = o;
}

// B[K=256][N] fp32 -> BT[Npad][256] bf16 (transposed, zero-padded rows)
__global__ __launch_bounds__(256) void cast_BT(const float* __restrict__ B,
                                               unsigned short* __restrict__ BT,
                                               int N, int Npad) {
    int i = blockIdx.x * blockDim.x + threadIdx.x;
    if (i >= Npad * 256) return;
    int n = i >> 8, k = i & 255;
    float v = (n < N) ? B[(size_t)k * N + n] : 0.f;
    BT[i] = f2bf(v);
}

// W3[256][484] -> BTcat[128][1024] bf16: BTcat[c][h*256+k] = 0.25*W3[k][h*121+c]
__global__ __launch_bounds__(256) void cast_BTcat(const float* __restrict__ W3,
                                                  unsigned short* __restrict__ BT) {
    int i = blockIdx.x * blockDim.x + threadIdx.x;  // 128*1024
    if (i >= 128 * 1024) return;
    int c = i >> 10, kk = i & 1023;
    int h = kk >> 8, k = kk & 255;
    float v = (c < NC) ? 0.25f * W3[(size_t)k * 484 + h * NC + c] : 0.f;
    BT[i] = f2bf(v);
}

// wl3[h*256+k] = sum_d W3[k][h*121+d]*al3[h][d]; wr3 likewise (i in [1024,2048))
__global__ __launch_bounds__(256) void wvec3_k(const float* __restrict__ W3,
                                               const float* __restrict__ al3,
                                               const float* __restrict__ ar3,
                                               float* __restrict__ wl3,
                                               float* __restrict__ wr3) {
    int i = blockIdx.x * blockDim.x + threadIdx.x;  // 2048
    if (i >= 2048) return;
    int j = i & 1023;
    int h = j >> 8, k = j & 255;
    const float* a = (i < 1024) ? al3 : ar3;
    const float* wrow = W3 + (size_t)k * 484 + h * NC;
    const float* arow = a + h * NC;
    float s = 0.f;
    for (int d = 0; d < NC; ++d) s += wrow[d] * arow[d];
    if (i < 1024) wl3[j] = s; else wr3[j] = s;
}

// ================= MFMA GEMM: C[M,Nout] = A[M,K] @ B[K,Nout] =================
// A bf16 [M][K]; BT bf16 [Npad][K]; out fp32 or bf16.
// 128x128 tile, 256 threads (4 waves 2x2), BK=32, 16x16x32 bf16 MFMA, 4x4 frags/wave.
__global__ __launch_bounds__(256) void gemm_bf16(const unsigned short* __restrict__ A,
                                                 const unsigned short* __restrict__ BT,
                                                 float* __restrict__ Cf,
                                                 unsigned short* __restrict__ Cb,
                                                 int M, int Nout, int K) {
    __shared__ __align__(16) unsigned short Alds[128 * 32];
    __shared__ __align__(16) unsigned short Blds[128 * 32];
    const int tid = threadIdx.x;
    const int wave = tid >> 6;
    const int lane = tid & 63;
    const int quad = lane >> 4;
    const int ml = lane & 15;
    const int m0 = blockIdx.x * 128;
    const int n0 = blockIdx.y * 128;
    const int wm0 = (wave >> 1) * 64;
    const int wn0 = (wave & 1) * 64;
    const int r = tid >> 2;
    const int c8 = (tid & 3) * 8;

    f32x4 acc[4][4] = {};

    for (int k0 = 0; k0 < K; k0 += 32) {
        #pragma unroll
        for (int p = 0; p < 2; ++p) {
            int rr = r + p * 64;
            int m = m0 + rr;
            uint4 va = make_uint4(0u, 0u, 0u, 0u);
            if (m < M) va = *(const uint4*)&A[(size_t)m * K + k0 + c8];
            *(uint4*)&Alds[rr * 32 + c8] = va;
            int n = n0 + rr;  // BT padded to grid => always in bounds
            uint4 vb = *(const uint4*)&BT[(size_t)n * K + k0 + c8];
            *(uint4*)&Blds[rr * 32 + c8] = vb;
        }
        __syncthreads();

        short8 af[4], bf[4];
        #pragma unroll
        for (int i = 0; i < 4; ++i)
            af[i] = *(const short8*)&Alds[(wm0 + i * 16 + ml) * 32 + quad * 8];
        #pragma unroll
        for (int j = 0; j < 4; ++j)
            bf[j] = *(const short8*)&Blds[(wn0 + j * 16 + ml) * 32 + quad * 8];
        #pragma unroll
        for (int i = 0; i < 4; ++i)
            #pragma unroll
            for (int j = 0; j < 4; ++j)
                acc[i][j] = __builtin_amdgcn_mfma_f32_16x16x32_bf16(af[i], bf[j], acc[i][j], 0, 0, 0);
        __syncthreads();
    }

    // C/D layout: col = lane&15, row = quad*4 + reg
    #pragma unroll
    for (int i = 0; i < 4; ++i) {
        #pragma unroll
        for (int reg = 0; reg < 4; ++reg) {
            int m = m0 + wm0 + i * 16 + quad * 4 + reg;
            if (m >= M) continue;
            #pragma unroll
            for (int j = 0; j < 4; ++j) {
                int n = n0 + wn0 + j * 16 + ml;
                if (n < Nout) {
                    if (Cb) Cb[(size_t)m * Nout + n] = f2bf(acc[i][j][reg]);
                    else    Cf[(size_t)m * Nout + n] = acc[i][j][reg];
                }
            }
        }
    }
}

// ================= per-node attention logits (bf16 feat), one wave per node =========
// feat row [256] = [h=lane>>4][d=(lane&15)*4 ..+3]; 16-lane group reduce per head.
__global__ __launch_bounds__(256) void node_attn(const unsigned short* __restrict__ feat,
                                                 const float* __restrict__ al,
                                                 const float* __restrict__ ar,
                                                 float* __restrict__ el,
                                                 float* __restrict__ er) {
    int wid = (blockIdx.x * blockDim.x + threadIdx.x) >> 6;
    int lane = threadIdx.x & 63;
    if (wid >= NN) return;
    int h = lane >> 4;
    int dl = (lane & 15) * 4;
    ushort4 xv = *(const ushort4*)&feat[(size_t)wid * 256 + lane * 4];
    float4 a4 = *(const float4*)&al[h * 64 + dl];
    float4 r4 = *(const float4*)&ar[h * 64 + dl];
    float f0 = bf2f(xv.x), f1 = bf2f(xv.y), f2 = bf2f(xv.z), f3 = bf2f(xv.w);
    float sl = f0 * a4.x + f1 * a4.y + f2 * a4.z + f3 * a4.w;
    float sr = f0 * r4.x + f1 * r4.y + f2 * r4.z + f3 * r4.w;
    #pragma unroll
    for (int off = 8; off; off >>= 1) {
        sl += __shfl_xor(sl, off);
        sr += __shfl_xor(sr, off);
    }
    if ((lane & 15) == 0) {
        el[wid * 4 + h] = sl;
        er[wid * 4 + h] = sr;
    }
}

// ================= layer-3 logits: el[n,h] = x[n] . wl3[h], full 256-dot =========
__global__ __launch_bounds__(256) void elr3_k(const unsigned short* __restrict__ x,
                                              const float* __restrict__ wl3,
                                              const float* __restrict__ wr3,
                                              float* __restrict__ el,
                                              float* __restrict__ er) {
    int wid = (blockIdx.x * blockDim.x + threadIdx.x) >> 6;
    int lane = threadIdx.x & 63;
    if (wid >= NN) return;
    ushort4 xv = *(const ushort4*)&x[(size_t)wid * 256 + lane * 4];
    float f[4] = {bf2f(xv.x), bf2f(xv.y), bf2f(xv.z), bf2f(xv.w)};
    float sl[4] = {}, sr[4] = {};
    #pragma unroll
    for (int h = 0; h < 4; ++h) {
        float4 a4 = *(const float4*)&wl3[h * 256 + lane * 4];
        float4 r4 = *(const float4*)&wr3[h * 256 + lane * 4];
        sl[h] = f[0] * a4.x + f[1] * a4.y + f[2] * a4.z + f[3] * a4.w;
        sr[h] = f[0] * r4.x + f[1] * r4.y + f[2] * r4.z + f[3] * r4.w;
    }
    #pragma unroll
    for (int off = 32; off; off >>= 1) {
        #pragma unroll
        for (int h = 0; h < 4; ++h) {
            sl[h] += __shfl_xor(sl[h], off);
            sr[h] += __shfl_xor(sr[h], off);
        }
    }
    if (lane == 0) {
        #pragma unroll
        for (int h = 0; h < 4; ++h) {
            el[wid * 4 + h] = sl[h];
            er[wid * 4 + h] = sr[h];
        }
    }
}

// ================= CSR build =================
__global__ __launch_bounds__(256) void hist_k(const int* __restrict__ dst, int* __restrict__ deg) {
    int e = blockIdx.x * blockDim.x + threadIdx.x;
    if (e < NE) atomicAdd(&deg[dst[e]], 1);
}

__global__ __launch_bounds__(256) void scan1(const int* __restrict__ deg,
                                             int* __restrict__ excl,
                                             int* __restrict__ partials) {
    __shared__ int sh[256];
    int i = blockIdx.x * 256 + threadIdx.x;
    int v = (i < NN) ? deg[i] : 0;
    sh[threadIdx.x] = v;
    __syncthreads();
    for (int off = 1; off < 256; off <<= 1) {
        int t = (threadIdx.x >= off) ? sh[threadIdx.x - off] : 0;
        __syncthreads();
        sh[threadIdx.x] += t;
        __syncthreads();
    }
    if (i < NN) excl[i] = sh[threadIdx.x] - v;
    if (threadIdx.x == 255) partials[blockIdx.x] = sh[255];
}

__global__ __launch_bounds__(256) void scan2(int* __restrict__ partials, int nb) {
    __shared__ int sh[256];
    int t = threadIdx.x;
    int v = (t < nb) ? partials[t] : 0;
    sh[t] = v;
    __syncthreads();
    for (int off = 1; off < 256; off <<= 1) {
        int x = (t >= off) ? sh[t - off] : 0;
        __syncthreads();
        sh[t] += x;
        __syncthreads();
    }
    if (t < nb) partials[t] = sh[t] - v;
}

__global__ __launch_bounds__(256) void scan3(const int* __restrict__ excl,
                                             const int* __restrict__ partials,
                                             int* __restrict__ rowptr) {
    int i = blockIdx.x * 256 + threadIdx.x;
    if (i < NN) rowptr[i] = excl[i] + partials[blockIdx.x];
}

__global__ __launch_bounds__(256) void scatter_k(const int* __restrict__ src,
                                                 const int* __restrict__ dst,
                                                 const int* __restrict__ rowptr,
                                                 int* __restrict__ cursor,
                                                 int* __restrict__ ssrc) {
    int e = blockIdx.x * blockDim.x + threadIdx.x;
    if (e >= NE) return;
    int d = dst[e];
    int p = atomicAdd(&cursor[d], 1);
    ssrc[rowptr[d] + p] = src[e];
}

// ===== fused softmax + aggregation + ELU (layers 1/2): bf16 feat -> bf16 out ========
__global__ __launch_bounds__(256) void agg256(const int* __restrict__ rowptr,
                                              const int* __restrict__ deg,
                                              const int* __restrict__ ssrc,
                                              const float* __restrict__ el,
                                              const float* __restrict__ er,
                                              const unsigned short* __restrict__ feat,
                                              unsigned short* __restrict__ ybf) {
    int wid = (blockIdx.x * blockDim.x + threadIdx.x) >> 6;
    int lane = threadIdx.x & 63;
    if (wid >= NN) return;
    int n = wid;
    int start = rowptr[n], cnt = deg[n];
    int head = lane >> 4;
    float ern = er[n * 4 + head];
    float m = -1e30f;
    for (int k = 0; k < cnt; ++k) {
        int s = ssrc[start + k];
        float v = el[s * 4 + head] + ern;
        v = v > 0.f ? v : 0.2f * v;
        m = fmaxf(m, v);
    }
    float ax = 0.f, ay = 0.f, az = 0.f, aw = 0.f, ssum = 0.f;
    for (int k = 0; k < cnt; ++k) {
        int s = ssrc[start + k];
        float v = el[s * 4 + head] + ern;
        v = v > 0.f ? v : 0.2f * v;
        float ex = __expf(v - m);
        ssum += ex;
        ushort4 fv = *(const ushort4*)&feat[(size_t)s * 256 + lane * 4];
        ax += ex * bf2f(fv.x); ay += ex * bf2f(fv.y);
        az += ex * bf2f(fv.z); aw += ex * bf2f(fv.w);
    }
    float inv = cnt ? 1.0f / ssum : 0.f;
    ax *= inv; ay *= inv; az *= inv; aw *= inv;
    ax = ax > 0.f ? ax : (__expf(ax) - 1.f);
    ay = ay > 0.f ? ay : (__expf(ay) - 1.f);
    az = az > 0.f ? az : (__expf(az) - 1.f);
    aw = aw > 0.f ? aw : (__expf(aw) - 1.f);
    ushort4 o;
    o.x = f2bf(ax); o.y = f2bf(ay); o.z = f2bf(az); o.w = f2bf(aw);
    *(ushort4*)&ybf[(size_t)n * 256 + lane * 4] = o;
}

// ===== layer 3: aggregate INPUT x2 rows per head -> xagg[N][4][256] bf16 ===========
__global__ __launch_bounds__(256) void agg3(const int* __restrict__ rowptr,
                                            const int* __restrict__ deg,
                                            const int* __restrict__ ssrc,
                                            const float* __restrict__ el,
                                            const float* __restrict__ er,
                                            const unsigned short* __restrict__ x,
                                            unsigned short* __restrict__ xagg) {
    int wid = (blockIdx.x * blockDim.x + threadIdx.x) >> 6;
    int lane = threadIdx.x & 63;
    if (wid >= NN) return;
    int n = wid;
    int start = rowptr[n], cnt = deg[n];
    float er0 = er[n * 4 + 0], er1 = er[n * 4 + 1], er2 = er[n * 4 + 2], er3 = er[n * 4 + 3];
    float m0 = -1e30f, m1 = -1e30f, m2 = -1e30f, m3 = -1e30f;
    for (int k = 0; k < cnt; ++k) {
        int s = ssrc[start + k];
        float v0 = el[s * 4 + 0] + er0; v0 = v0 > 0.f ? v0 : 0.2f * v0; m0 = fmaxf(m0, v0);
        float v1 = el[s * 4 + 1] + er1; v1 = v1 > 0.f ? v1 : 0.2f * v1; m1 = fmaxf(m1, v1);
        float v2 = el[s * 4 + 2] + er2; v2 = v2 > 0.f ? v2 : 0.2f * v2; m2 = fmaxf(m2, v2);
        float v3 = el[s * 4 + 3] + er3; v3 = v3 > 0.f ? v3 : 0.2f * v3; m3 = fmaxf(m3, v3);
    }
    float acc[4][4] = {};
    float s0 = 0.f, s1 = 0.f, s2 = 0.f, s3 = 0.f;
    for (int k = 0; k < cnt; ++k) {
        int s = ssrc[start + k];
        float v0 = el[s * 4 + 0] + er0; v0 = v0 > 0.f ? v0 : 0.2f * v0;
        float v1 = el[s * 4 + 1] + er1; v1 = v1 > 0.f ? v1 : 0.2f * v1;
        float v2 = el[s * 4 + 2] + er2; v2 = v2 > 0.f ? v2 : 0.2f * v2;
        float v3 = el[s * 4 + 3] + er3; v3 = v3 > 0.f ? v3 : 0.2f * v3;
        float e0 = __expf(v0 - m0), e1 = __expf(v1 - m1);
        float e2 = __expf(v2 - m2), e3 = __expf(v3 - m3);
        s0 += e0; s1 += e1; s2 += e2; s3 += e3;
        ushort4 xv = *(const ushort4*)&x[(size_t)s * 256 + lane * 4];
        float f0 = bf2f(xv.x), f1 = bf2f(xv.y), f2 = bf2f(xv.z), f3 = bf2f(xv.w);
        acc[0][0] += e0 * f0; acc[0][1] += e0 * f1; acc[0][2] += e0 * f2; acc[0][3] += e0 * f3;
        acc[1][0] += e1 * f0; acc[1][1] += e1 * f1; acc[1][2] += e1 * f2; acc[1][3] += e1 * f3;
        acc[2][0] += e2 * f0; acc[2][1] += e2 * f1; acc[2][2] += e2 * f2; acc[2][3] += e2 * f3;
        acc[3][0] += e3 * f0; acc[3][1] += e3 * f1; acc[3][2] += e3 * f2; acc[3][3] += e3 * f3;
    }
    float inv[4];
    inv[0] = cnt ? 1.f / s0 : 0.f; inv[1] = cnt ? 1.f / s1 : 0.f;
    inv[2] = cnt ? 1.f / s2 : 0.f; inv[3] = cnt ? 1.f / s3 : 0.f;
    #pragma unroll
    for (int h = 0; h < 4; ++h) {
        ushort4 o;
        o.x = f2bf(acc[h][0] * inv[h]); o.y = f2bf(acc[h][1] * inv[h]);
        o.z = f2bf(acc[h][2] * inv[h]); o.w = f2bf(acc[h][3] * inv[h]);
        *(ushort4*)&xagg[(size_t)n * 1024 + h * 256 + lane * 4] = o;
    }
}

extern "C" void kernel_launch(void* const* d_in, const int* in_sizes, int n_in,
                              void* d_out, int out_size, void* d_ws, size_t ws_size,
                              hipStream_t stream) {
    const float* h   = (const float*)d_in[0];
    const int*   src = (const int*)d_in[1];
    const int*   dst = (const int*)d_in[2];
    const float* W1  = (const float*)d_in[3];
    const float* al1 = (const float*)d_in[4];
    const float* ar1 = (const float*)d_in[5];
    const float* W2  = (const float*)d_in[6];
    const float* al2 = (const float*)d_in[7];
    const float* ar2 = (const float*)d_in[8];
    const float* W3  = (const float*)d_in[9];
    const float* al3 = (const float*)d_in[10];
    const float* ar3 = (const float*)d_in[11];
    float* out = (float*)d_out;

    float* ws = (float*)d_ws;
    // workspace layout (float units):
    //  [0, 6.4M)      x_bf   (layer outputs x1/x2, bf16, live into L3)
    //  [6.4M, 12.8M)  h_bf   (dead after L1 gemm)
    //  [12.8M, 19.2M) feat_bf (dead after L2 agg)
    //  [6.4M, 32M)    xagg   (L3 only; overlays h_bf+feat_bf — both dead by then)
    unsigned short* x_bf    = (unsigned short*)ws;
    unsigned short* h_bf    = (unsigned short*)(ws + 6400000);
    unsigned short* feat_bf = (unsigned short*)(ws + 12800000);
    unsigned short* xagg    = (unsigned short*)(ws + 6400000);
    float* el  = ws + 32000000;
    float* er  = ws + 32200000;
    float* wl3 = ws + 32400000;           // 1024
    float* wr3 = ws + 32401024;           // 1024
    unsigned short* BT1   = (unsigned short*)(ws + 32402048);  // 65,536 bf16
    unsigned short* BT2   = (unsigned short*)(ws + 32434816);  // 65,536 bf16
    unsigned short* BTcat = (unsigned short*)(ws + 32467584);  // 131,072 bf16
    int* ibase  = (int*)(ws + 32533120);
    int* deg      = ibase;
    int* excl     = ibase + 50000;
    int* partials = ibase + 100000;
    int* rowptr   = ibase + 100256;
    int* cursor   = ibase + 150256;
    int* ssrc     = ibase + 200256;

    const int NB = (NN + 255) / 256;

    // ---- CSR build ----
    hipMemsetAsync(deg, 0, NN * sizeof(int), stream);
    hipMemsetAsync(cursor, 0, NN * sizeof(int), stream);
    hist_k<<<(NE + 255) / 256, 256, 0, stream>>>(dst, deg);
    scan1<<<NB, 256, 0, stream>>>(deg, excl, partials);
    scan2<<<1, 256, 0, stream>>>(partials, NB);
    scan3<<<NB, 256, 0, stream>>>(excl, partials, rowptr);
    scatter_k<<<(NE + 255) / 256, 256, 0, stream>>>(src, dst, rowptr, cursor, ssrc);

    // ---- casts / weight prep ----
    cast_x<<<(NN * 256 / 4 + 255) / 256, 256, 0, stream>>>(h, h_bf, NN * 256 / 4);
    cast_BT<<<(256 * 256 + 255) / 256, 256, 0, stream>>>(W1, BT1, 256, 256);
    cast_BT<<<(256 * 256 + 255) / 256, 256, 0, stream>>>(W2, BT2, 256, 256);
    cast_BTcat<<<512, 256, 0, stream>>>(W3, BTcat);
    wvec3_k<<<8, 256, 0, stream>>>(W3, al3, ar3, wl3, wr3);

    dim3 g256((NN + 127) / 128, 2);
    dim3 gOut((NN + 127) / 128, 1);
    const int WAVE_BLOCKS = (NN * 64 + 255) / 256;  // one wave per node

    // ---- layer 1 ----
    gemm_bf16<<<g256, 256, 0, stream>>>(h_bf, BT1, nullptr, feat_bf, NN, 256, 256);
    node_attn<<<WAVE_BLOCKS, 256, 0, stream>>>(feat_bf, al1, ar1, el, er);
    agg256<<<WAVE_BLOCKS, 256, 0, stream>>>(rowptr, deg, ssrc, el, er, feat_bf, x_bf);

    // ---- layer 2 ----
    gemm_bf16<<<g256, 256, 0, stream>>>(x_bf, BT2, nullptr, feat_bf, NN, 256, 256);
    node_attn<<<WAVE_BLOCKS, 256, 0, stream>>>(feat_bf, al2, ar2, el, er);
    agg256<<<WAVE_BLOCKS, 256, 0, stream>>>(rowptr, deg, ssrc, el, er, feat_bf, x_bf);

    // ---- layer 3 (input-side aggregation; exact reorder of reference math) ----
    elr3_k<<<WAVE_BLOCKS, 256, 0, stream>>>(x_bf, wl3, wr3, el, er);
    agg3<<<WAVE_BLOCKS, 256, 0, stream>>>(rowptr, deg, ssrc, el, er, x_bf, xagg);
    gemm_bf16<<<gOut, 256, 0, stream>>>(xagg, BTcat, out, nullptr, NN, NC, 1024);
}

// Round 5
// 456.608 us; speedup vs baseline: 9.2532x; 1.2231x over previous
//
#include <hip/hip_runtime.h>
#include <cstddef>

#define NN 50000
#define NE 400000
#define NH 4
#define NC 121
#define MAXSLOT 600000   // NE + 4*NN upper bound on padded CSR slots

typedef __attribute__((ext_vector_type(8))) short short8;
typedef __attribute__((ext_vector_type(4))) float f32x4;

// fp32 -> bf16 round-to-nearest-even
static __device__ __forceinline__ unsigned short f2bf(float f) {
    unsigned u = __float_as_uint(f);
    u += 0x7fffu + ((u >> 16) & 1u);
    return (unsigned short)(u >> 16);
}
static __device__ __forceinline__ float bf2f(unsigned short u) {
    return __uint_as_float(((unsigned)u) << 16);
}

// ================= cast kernels =================
__global__ __launch_bounds__(256) void cast_x(const float* __restrict__ in,
                                              unsigned short* __restrict__ out, int n4) {
    int i = blockIdx.x * blockDim.x + threadIdx.x;
    if (i >= n4) return;
    float4 v = *(const float4*)&in[i * 4];
    ushort4 o;
    o.x = f2bf(v.x); o.y = f2bf(v.y); o.z = f2bf(v.z); o.w = f2bf(v.w);
    *(ushort4*)&out[i * 4] = o;
}

__global__ __launch_bounds__(256) void cast_BT(const float* __restrict__ B,
                                               unsigned short* __restrict__ BT,
                                               int N, int Npad) {
    int i = blockIdx.x * blockDim.x + threadIdx.x;
    if (i >= Npad * 256) return;
    int n = i >> 8, k = i & 255;
    float v = (n < N) ? B[(size_t)k * N + n] : 0.f;
    BT[i] = f2bf(v);
}

// W3[256][484] -> BTcat[128][1024] bf16: BTcat[c][h*256+k] = 0.25*W3[k][h*121+c]
__global__ __launch_bounds__(256) void cast_BTcat(const float* __restrict__ W3,
                                                  unsigned short* __restrict__ BT) {
    int i = blockIdx.x * blockDim.x + threadIdx.x;
    if (i >= 128 * 1024) return;
    int c = i >> 10, kk = i & 1023;
    int h = kk >> 8, k = kk & 255;
    float v = (c < NC) ? 0.25f * W3[(size_t)k * 484 + h * NC + c] : 0.f;
    BT[i] = f2bf(v);
}

// wl3[h*256+k] = sum_d W3[k][h*121+d]*al3[h][d]; wr3 likewise
__global__ __launch_bounds__(256) void wvec3_k(const float* __restrict__ W3,
                                               const float* __restrict__ al3,
                                               const float* __restrict__ ar3,
                                               float* __restrict__ wl3,
                                               float* __restrict__ wr3) {
    int i = blockIdx.x * blockDim.x + threadIdx.x;
    if (i >= 2048) return;
    int j = i & 1023;
    int h = j >> 8, k = j & 255;
    const float* a = (i < 1024) ? al3 : ar3;
    const float* wrow = W3 + (size_t)k * 484 + h * NC;
    const float* arow = a + h * NC;
    float s = 0.f;
    for (int d = 0; d < NC; ++d) s += wrow[d] * arow[d];
    if (i < 1024) wl3[j] = s; else wr3[j] = s;
}

// ================= MFMA GEMM (unchanged structure) =================
__global__ __launch_bounds__(256) void gemm_bf16(const unsigned short* __restrict__ A,
                                                 const unsigned short* __restrict__ BT,
                                                 float* __restrict__ Cf,
                                                 unsigned short* __restrict__ Cb,
                                                 int M, int Nout, int K) {
    __shared__ __align__(16) unsigned short Alds[128 * 32];
    __shared__ __align__(16) unsigned short Blds[128 * 32];
    const int tid = threadIdx.x;
    const int wave = tid >> 6;
    const int lane = tid & 63;
    const int quad = lane >> 4;
    const int ml = lane & 15;
    const int m0 = blockIdx.x * 128;
    const int n0 = blockIdx.y * 128;
    const int wm0 = (wave >> 1) * 64;
    const int wn0 = (wave & 1) * 64;
    const int r = tid >> 2;
    const int c8 = (tid & 3) * 8;

    f32x4 acc[4][4] = {};

    for (int k0 = 0; k0 < K; k0 += 32) {
        #pragma unroll
        for (int p = 0; p < 2; ++p) {
            int rr = r + p * 64;
            int m = m0 + rr;
            uint4 va = make_uint4(0u, 0u, 0u, 0u);
            if (m < M) va = *(const uint4*)&A[(size_t)m * K + k0 + c8];
            *(uint4*)&Alds[rr * 32 + c8] = va;
            int n = n0 + rr;
            uint4 vb = *(const uint4*)&BT[(size_t)n * K + k0 + c8];
            *(uint4*)&Blds[rr * 32 + c8] = vb;
        }
        __syncthreads();

        short8 af[4], bf[4];
        #pragma unroll
        for (int i = 0; i < 4; ++i)
            af[i] = *(const short8*)&Alds[(wm0 + i * 16 + ml) * 32 + quad * 8];
        #pragma unroll
        for (int j = 0; j < 4; ++j)
            bf[j] = *(const short8*)&Blds[(wn0 + j * 16 + ml) * 32 + quad * 8];
        #pragma unroll
        for (int i = 0; i < 4; ++i)
            #pragma unroll
            for (int j = 0; j < 4; ++j)
                acc[i][j] = __builtin_amdgcn_mfma_f32_16x16x32_bf16(af[i], bf[j], acc[i][j], 0, 0, 0);
        __syncthreads();
    }

    #pragma unroll
    for (int i = 0; i < 4; ++i) {
        #pragma unroll
        for (int reg = 0; reg < 4; ++reg) {
            int m = m0 + wm0 + i * 16 + quad * 4 + reg;
            if (m >= M) continue;
            #pragma unroll
            for (int j = 0; j < 4; ++j) {
                int n = n0 + wn0 + j * 16 + ml;
                if (n < Nout) {
                    if (Cb) Cb[(size_t)m * Nout + n] = f2bf(acc[i][j][reg]);
                    else    Cf[(size_t)m * Nout + n] = acc[i][j][reg];
                }
            }
        }
    }
}

// ================= per-node attention logits (bf16 feat), one wave per node =========
__global__ __launch_bounds__(256) void node_attn(const unsigned short* __restrict__ feat,
                                                 const float* __restrict__ al,
                                                 const float* __restrict__ ar,
                                                 float* __restrict__ el,
                                                 float* __restrict__ er) {
    int wid = (blockIdx.x * blockDim.x + threadIdx.x) >> 6;
    int lane = threadIdx.x & 63;
    if (wid >= NN) return;
    int h = lane >> 4;
    int dl = (lane & 15) * 4;
    ushort4 xv = *(const ushort4*)&feat[(size_t)wid * 256 + lane * 4];
    float4 a4 = *(const float4*)&al[h * 64 + dl];
    float4 r4 = *(const float4*)&ar[h * 64 + dl];
    float f0 = bf2f(xv.x), f1 = bf2f(xv.y), f2 = bf2f(xv.z), f3 = bf2f(xv.w);
    float sl = f0 * a4.x + f1 * a4.y + f2 * a4.z + f3 * a4.w;
    float sr = f0 * r4.x + f1 * r4.y + f2 * r4.z + f3 * r4.w;
    #pragma unroll
    for (int off = 8; off; off >>= 1) {
        sl += __shfl_xor(sl, off);
        sr += __shfl_xor(sr, off);
    }
    if ((lane & 15) == 0) {
        el[wid * 4 + h] = sl;
        er[wid * 4 + h] = sr;
    }
}

// ================= layer-3 logits =================
__global__ __launch_bounds__(256) void elr3_k(const unsigned short* __restrict__ x,
                                              const float* __restrict__ wl3,
                                              const float* __restrict__ wr3,
                                              float* __restrict__ el,
                                              float* __restrict__ er) {
    int wid = (blockIdx.x * blockDim.x + threadIdx.x) >> 6;
    int lane = threadIdx.x & 63;
    if (wid >= NN) return;
    ushort4 xv = *(const ushort4*)&x[(size_t)wid * 256 + lane * 4];
    float f[4] = {bf2f(xv.x), bf2f(xv.y), bf2f(xv.z), bf2f(xv.w)};
    float sl[4] = {}, sr[4] = {};
    #pragma unroll
    for (int h = 0; h < 4; ++h) {
        float4 a4 = *(const float4*)&wl3[h * 256 + lane * 4];
        float4 r4 = *(const float4*)&wr3[h * 256 + lane * 4];
        sl[h] = f[0] * a4.x + f[1] * a4.y + f[2] * a4.z + f[3] * a4.w;
        sr[h] = f[0] * r4.x + f[1] * r4.y + f[2] * r4.z + f[3] * r4.w;
    }
    #pragma unroll
    for (int off = 32; off; off >>= 1) {
        #pragma unroll
        for (int h = 0; h < 4; ++h) {
            sl[h] += __shfl_xor(sl[h], off);
            sr[h] += __shfl_xor(sr[h], off);
        }
    }
    if (lane == 0) {
        #pragma unroll
        for (int h = 0; h < 4; ++h) {
            el[wid * 4 + h] = sl[h];
            er[wid * 4 + h] = sr[h];
        }
    }
}

// ================= CSR build (4-padded rows) =================
__global__ __launch_bounds__(256) void hist_k(const int* __restrict__ dst, int* __restrict__ deg) {
    int e = blockIdx.x * blockDim.x + threadIdx.x;
    if (e < NE) atomicAdd(&deg[dst[e]], 1);
}

__global__ __launch_bounds__(256) void scan1(const int* __restrict__ deg,
                                             int* __restrict__ excl,
                                             int* __restrict__ partials) {
    __shared__ int sh[256];
    int i = blockIdx.x * 256 + threadIdx.x;
    int v = (i < NN) ? ((deg[i] + 3) & ~3) : 0;   // pad each row to multiple of 4
    sh[threadIdx.x] = v;
    __syncthreads();
    for (int off = 1; off < 256; off <<= 1) {
        int t = (threadIdx.x >= off) ? sh[threadIdx.x - off] : 0;
        __syncthreads();
        sh[threadIdx.x] += t;
        __syncthreads();
    }
    if (i < NN) excl[i] = sh[threadIdx.x] - v;
    if (threadIdx.x == 255) partials[blockIdx.x] = sh[255];
}

__global__ __launch_bounds__(256) void scan2(int* __restrict__ partials, int nb) {
    __shared__ int sh[256];
    int t = threadIdx.x;
    int v = (t < nb) ? partials[t] : 0;
    sh[t] = v;
    __syncthreads();
    for (int off = 1; off < 256; off <<= 1) {
        int x = (t >= off) ? sh[t - off] : 0;
        __syncthreads();
        sh[t] += x;
        __syncthreads();
    }
    if (t < nb) partials[t] = sh[t] - v;
}

__global__ __launch_bounds__(256) void scan3(const int* __restrict__ excl,
                                             const int* __restrict__ partials,
                                             int* __restrict__ rowptr) {
    int i = blockIdx.x * 256 + threadIdx.x;
    if (i < NN) rowptr[i] = excl[i] + partials[blockIdx.x];
}

// scatter src AND dst into padded CSR slots (pads stay: ssrc=0, sdst=-1 from memsets)
__global__ __launch_bounds__(256) void scatter_k(const int* __restrict__ src,
                                                 const int* __restrict__ dst,
                                                 const int* __restrict__ rowptr,
                                                 int* __restrict__ cursor,
                                                 int* __restrict__ ssrc,
                                                 int* __restrict__ sdst) {
    int e = blockIdx.x * blockDim.x + threadIdx.x;
    if (e >= NE) return;
    int d = dst[e];
    int p = atomicAdd(&cursor[d], 1);
    int pos = rowptr[d] + p;
    ssrc[pos] = src[e];
    sdst[pos] = d;
}

// ===== per-CSR-slot unnormalized weights, head-planar: wcsr[h*MAXSLOT+pos] =========
// single-pass softmax (no max subtraction — logits are O(5), exp is safe in fp32)
__global__ __launch_bounds__(256) void edgew_k(const int* __restrict__ ssrc,
                                               const int* __restrict__ sdst,
                                               const float* __restrict__ el,
                                               const float* __restrict__ er,
                                               float* __restrict__ wcsr) {
    int i = blockIdx.x * blockDim.x + threadIdx.x;
    if (i >= MAXSLOT) return;
    int d = sdst[i];
    float w0 = 0.f, w1 = 0.f, w2 = 0.f, w3 = 0.f;
    if (d >= 0) {
        int s = ssrc[i];
        float4 e_l = *(const float4*)&el[s * 4];
        float4 e_r = *(const float4*)&er[d * 4];
        float v0 = e_l.x + e_r.x; v0 = v0 > 0.f ? v0 : 0.2f * v0;
        float v1 = e_l.y + e_r.y; v1 = v1 > 0.f ? v1 : 0.2f * v1;
        float v2 = e_l.z + e_r.z; v2 = v2 > 0.f ? v2 : 0.2f * v2;
        float v3 = e_l.w + e_r.w; v3 = v3 > 0.f ? v3 : 0.2f * v3;
        w0 = __expf(v0); w1 = __expf(v1); w2 = __expf(v2); w3 = __expf(v3);
    }
    wcsr[0 * MAXSLOT + i] = w0;
    wcsr[1 * MAXSLOT + i] = w1;
    wcsr[2 * MAXSLOT + i] = w2;
    wcsr[3 * MAXSLOT + i] = w3;
}

// ===== layers 1/2 aggregation: single pass, x4 unrolled, bf16 in/out, fused ELU =====
__global__ __launch_bounds__(256) void agg256(const int* __restrict__ rowptr,
                                              const int* __restrict__ deg,
                                              const int* __restrict__ ssrc,
                                              const float* __restrict__ wcsr,
                                              const unsigned short* __restrict__ feat,
                                              unsigned short* __restrict__ ybf) {
    int wid = (blockIdx.x * blockDim.x + threadIdx.x) >> 6;
    int lane = threadIdx.x & 63;
    if (wid >= NN) return;
    int n = wid;
    int start = rowptr[n];
    int cnt4 = (deg[n] + 3) & ~3;
    int head = lane >> 4;
    const float* wch = wcsr + (size_t)head * MAXSLOT;
    float ax = 0.f, ay = 0.f, az = 0.f, aw = 0.f, ssum = 0.f;
    for (int k = 0; k < cnt4; k += 4) {
        int4 sv = *(const int4*)&ssrc[start + k];
        float4 w4 = *(const float4*)&wch[start + k];
        ushort4 f0 = *(const ushort4*)&feat[(size_t)sv.x * 256 + lane * 4];
        ushort4 f1 = *(const ushort4*)&feat[(size_t)sv.y * 256 + lane * 4];
        ushort4 f2 = *(const ushort4*)&feat[(size_t)sv.z * 256 + lane * 4];
        ushort4 f3 = *(const ushort4*)&feat[(size_t)sv.w * 256 + lane * 4];
        ssum += (w4.x + w4.y) + (w4.z + w4.w);
        ax += w4.x * bf2f(f0.x) + w4.y * bf2f(f1.x) + w4.z * bf2f(f2.x) + w4.w * bf2f(f3.x);
        ay += w4.x * bf2f(f0.y) + w4.y * bf2f(f1.y) + w4.z * bf2f(f2.y) + w4.w * bf2f(f3.y);
        az += w4.x * bf2f(f0.z) + w4.y * bf2f(f1.z) + w4.z * bf2f(f2.z) + w4.w * bf2f(f3.z);
        aw += w4.x * bf2f(f0.w) + w4.y * bf2f(f1.w) + w4.z * bf2f(f2.w) + w4.w * bf2f(f3.w);
    }
    float inv = ssum > 0.f ? 1.0f / ssum : 0.f;
    ax *= inv; ay *= inv; az *= inv; aw *= inv;
    ax = ax > 0.f ? ax : (__expf(ax) - 1.f);
    ay = ay > 0.f ? ay : (__expf(ay) - 1.f);
    az = az > 0.f ? az : (__expf(az) - 1.f);
    aw = aw > 0.f ? aw : (__expf(aw) - 1.f);
    ushort4 o;
    o.x = f2bf(ax); o.y = f2bf(ay); o.z = f2bf(az); o.w = f2bf(aw);
    *(ushort4*)&ybf[(size_t)n * 256 + lane * 4] = o;
}

// ===== layer 3: aggregate x2 rows per head -> xagg[N][4][256] bf16, x4 unrolled =====
__global__ __launch_bounds__(256) void agg3(const int* __restrict__ rowptr,
                                            const int* __restrict__ deg,
                                            const int* __restrict__ ssrc,
                                            const float* __restrict__ wcsr,
                                            const unsigned short* __restrict__ x,
                                            unsigned short* __restrict__ xagg) {
    int wid = (blockIdx.x * blockDim.x + threadIdx.x) >> 6;
    int lane = threadIdx.x & 63;
    if (wid >= NN) return;
    int n = wid;
    int start = rowptr[n];
    int cnt4 = (deg[n] + 3) & ~3;
    float acc[4][4] = {};
    float ssum[4] = {};
    for (int k = 0; k < cnt4; k += 4) {
        int4 sv = *(const int4*)&ssrc[start + k];
        float4 w0 = *(const float4*)&wcsr[0 * MAXSLOT + start + k];
        float4 w1 = *(const float4*)&wcsr[1 * MAXSLOT + start + k];
        float4 w2 = *(const float4*)&wcsr[2 * MAXSLOT + start + k];
        float4 w3 = *(const float4*)&wcsr[3 * MAXSLOT + start + k];
        ushort4 xa = *(const ushort4*)&x[(size_t)sv.x * 256 + lane * 4];
        ushort4 xb = *(const ushort4*)&x[(size_t)sv.y * 256 + lane * 4];
        ushort4 xc = *(const ushort4*)&x[(size_t)sv.z * 256 + lane * 4];
        ushort4 xd = *(const ushort4*)&x[(size_t)sv.w * 256 + lane * 4];
        ssum[0] += (w0.x + w0.y) + (w0.z + w0.w);
        ssum[1] += (w1.x + w1.y) + (w1.z + w1.w);
        ssum[2] += (w2.x + w2.y) + (w2.z + w2.w);
        ssum[3] += (w3.x + w3.y) + (w3.z + w3.w);
        float fa[4] = {bf2f(xa.x), bf2f(xa.y), bf2f(xa.z), bf2f(xa.w)};
        float fb[4] = {bf2f(xb.x), bf2f(xb.y), bf2f(xb.z), bf2f(xb.w)};
        float fc[4] = {bf2f(xc.x), bf2f(xc.y), bf2f(xc.z), bf2f(xc.w)};
        float fd[4] = {bf2f(xd.x), bf2f(xd.y), bf2f(xd.z), bf2f(xd.w)};
        #pragma unroll
        for (int d = 0; d < 4; ++d) {
            acc[0][d] += w0.x * fa[d] + w0.y * fb[d] + w0.z * fc[d] + w0.w * fd[d];
            acc[1][d] += w1.x * fa[d] + w1.y * fb[d] + w1.z * fc[d] + w1.w * fd[d];
            acc[2][d] += w2.x * fa[d] + w2.y * fb[d] + w2.z * fc[d] + w2.w * fd[d];
            acc[3][d] += w3.x * fa[d] + w3.y * fb[d] + w3.z * fc[d] + w3.w * fd[d];
        }
    }
    #pragma unroll
    for (int h = 0; h < 4; ++h) {
        float inv = ssum[h] > 0.f ? 1.f / ssum[h] : 0.f;
        ushort4 o;
        o.x = f2bf(acc[h][0] * inv); o.y = f2bf(acc[h][1] * inv);
        o.z = f2bf(acc[h][2] * inv); o.w = f2bf(acc[h][3] * inv);
        *(ushort4*)&xagg[(size_t)n * 1024 + h * 256 + lane * 4] = o;
    }
}

extern "C" void kernel_launch(void* const* d_in, const int* in_sizes, int n_in,
                              void* d_out, int out_size, void* d_ws, size_t ws_size,
                              hipStream_t stream) {
    const float* h   = (const float*)d_in[0];
    const int*   src = (const int*)d_in[1];
    const int*   dst = (const int*)d_in[2];
    const float* W1  = (const float*)d_in[3];
    const float* al1 = (const float*)d_in[4];
    const float* ar1 = (const float*)d_in[5];
    const float* W2  = (const float*)d_in[6];
    const float* al2 = (const float*)d_in[7];
    const float* ar2 = (const float*)d_in[8];
    const float* W3  = (const float*)d_in[9];
    const float* al3 = (const float*)d_in[10];
    const float* ar3 = (const float*)d_in[11];
    float* out = (float*)d_out;

    float* ws = (float*)d_ws;
    // workspace layout (float units):
    //  [0, 6.4M)      x_bf (x1/x2 bf16)
    //  [6.4M, 12.8M)  h_bf (dead after L1 gemm)
    //  [12.8M, 19.2M) feat_bf (dead after L2 agg)
    //  [6.4M, 32M)    xagg (L3 only, overlays h_bf+feat_bf)
    unsigned short* x_bf    = (unsigned short*)ws;
    unsigned short* h_bf    = (unsigned short*)(ws + 6400000);
    unsigned short* feat_bf = (unsigned short*)(ws + 12800000);
    unsigned short* xagg    = (unsigned short*)(ws + 6400000);
    float* el  = ws + 32000000;
    float* er  = ws + 32200000;
    float* wl3 = ws + 32400000;
    float* wr3 = ws + 32401024;
    unsigned short* BT1   = (unsigned short*)(ws + 32402048);
    unsigned short* BT2   = (unsigned short*)(ws + 32434816);
    unsigned short* BTcat = (unsigned short*)(ws + 32467584);
    float* wcsr = ws + 32533120;                 // 4 planes x 600,000 = 2.4M floats
    int* ibase  = (int*)(ws + 34933120);
    int* deg      = ibase;                       // 50,000
    int* excl     = ibase + 50000;               // 50,000
    int* partials = ibase + 100000;              // 256
    int* rowptr   = ibase + 100256;              // 50,000
    int* cursor   = ibase + 150256;              // 50,000
    int* ssrc     = ibase + 200256;              // 600,000 (padded slots)
    int* sdst     = ibase + 800256;              // 600,000

    const int NB = (NN + 255) / 256;
    const int SLOT_BLOCKS = (MAXSLOT + 255) / 256;

    // ---- CSR build (4-padded rows; pads: ssrc=0, sdst=-1) ----
    hipMemsetAsync(deg, 0, NN * sizeof(int), stream);
    hipMemsetAsync(cursor, 0, NN * sizeof(int), stream);
    hipMemsetAsync(ssrc, 0, MAXSLOT * sizeof(int), stream);
    hipMemsetAsync(sdst, 0xFF, MAXSLOT * sizeof(int), stream);
    hist_k<<<(NE + 255) / 256, 256, 0, stream>>>(dst, deg);
    scan1<<<NB, 256, 0, stream>>>(deg, excl, partials);
    scan2<<<1, 256, 0, stream>>>(partials, NB);
    scan3<<<NB, 256, 0, stream>>>(excl, partials, rowptr);
    scatter_k<<<(NE + 255) / 256, 256, 0, stream>>>(src, dst, rowptr, cursor, ssrc, sdst);

    // ---- casts / weight prep ----
    cast_x<<<(NN * 256 / 4 + 255) / 256, 256, 0, stream>>>(h, h_bf, NN * 256 / 4);
    cast_BT<<<(256 * 256 + 255) / 256, 256, 0, stream>>>(W1, BT1, 256, 256);
    cast_BT<<<(256 * 256 + 255) / 256, 256, 0, stream>>>(W2, BT2, 256, 256);
    cast_BTcat<<<512, 256, 0, stream>>>(W3, BTcat);
    wvec3_k<<<8, 256, 0, stream>>>(W3, al3, ar3, wl3, wr3);

    dim3 g256((NN + 127) / 128, 2);
    dim3 gOut((NN + 127) / 128, 1);
    const int WAVE_BLOCKS = (NN * 64 + 255) / 256;

    // ---- layer 1 ----
    gemm_bf16<<<g256, 256, 0, stream>>>(h_bf, BT1, nullptr, feat_bf, NN, 256, 256);
    node_attn<<<WAVE_BLOCKS, 256, 0, stream>>>(feat_bf, al1, ar1, el, er);
    edgew_k<<<SLOT_BLOCKS, 256, 0, stream>>>(ssrc, sdst, el, er, wcsr);
    agg256<<<WAVE_BLOCKS, 256, 0, stream>>>(rowptr, deg, ssrc, wcsr, feat_bf, x_bf);

    // ---- layer 2 ----
    gemm_bf16<<<g256, 256, 0, stream>>>(x_bf, BT2, nullptr, feat_bf, NN, 256, 256);
    node_attn<<<WAVE_BLOCKS, 256, 0, stream>>>(feat_bf, al2, ar2, el, er);
    edgew_k<<<SLOT_BLOCKS, 256, 0, stream>>>(ssrc, sdst, el, er, wcsr);
    agg256<<<WAVE_BLOCKS, 256, 0, stream>>>(rowptr, deg, ssrc, wcsr, feat_bf, x_bf);

    // ---- layer 3 (input-side aggregation; exact reorder of reference math) ----
    elr3_k<<<WAVE_BLOCKS, 256, 0, stream>>>(x_bf, wl3, wr3, el, er);
    edgew_k<<<SLOT_BLOCKS, 256, 0, stream>>>(ssrc, sdst, el, er, wcsr);
    agg3<<<WAVE_BLOCKS, 256, 0, stream>>>(rowptr, deg, ssrc, wcsr, x_bf, xagg);
    gemm_bf16<<<gOut, 256, 0, stream>>>(xagg, BTcat, out, nullptr, NN, NC, 1024);
}